// Round 13
// baseline (159.087 us; speedup 1.0000x reference)
//
#include <hip/hip_runtime.h>

// HaloAttention. B=2, H=W=128, C=128, NH=4, hd=32, WS=16, HS=8, WSH=32.
// R18: R17 + finish the L2-locality job (the one axis that keeps winning):
// - swizzle decode win=logical&127, head=logical>>7: each XCD owns one full
//   batch image x one head -> working set ~2MB, fully L2-resident (was ~6MB
//   with 16win x 4head: K/V+bias+Q thrash the 4MB L2).
// - Q head-major Qh[head][pix][32] (gemm_qkv store unified with K/V);
//   halo Q reads dense, per-XCD Q footprint /4.
// - O head-major Ob[head][pix][32]; halo O-writes 64B-stride; gemm_proj
//   stages from 4 dense head streams.
// Mapping/layout only; numerics byte-identical to R17.

typedef unsigned short ushort_t;
typedef __attribute__((ext_vector_type(8))) short bf16x8;
typedef __attribute__((ext_vector_type(4))) float floatx4;

#define NHEADS 4
#define BTBL 2209          // 47*47 bias table rows
#define PK 64              // key stride (bf16) for P/Vt LDS rows (128B, aligned)
#define LOG2E 1.4426950408889634f
#define QSCALE (0.17677669529663687f * LOG2E)   // head_dim^-0.5 * log2(e)

__device__ __forceinline__ int reflect_idx(int p) {
    p = (p < 0) ? -p : p;
    p = (p > 127) ? 254 - p : p;
    return p;
}

// fp32 -> bf16 bits, RNE
__device__ __forceinline__ ushort_t f2b(float x) {
    unsigned u = __float_as_uint(x);
    return (ushort_t)((u + 0x7fffu + ((u >> 16) & 1u)) >> 16);
}

// ---------------------------------------------------------------------------
// Fused prep: blocks [0,257) pack weights/biases; blocks [257,1281) build the
// bf16 bias fragments (pre-scaled by log2e).
// Fragment layout: [h(4)][kt(64)][wave(4)][lane(64)][qt(4)][reg(4)] ushort.
__global__ __launch_bounds__(256) void prep(
    const float* __restrict__ Wq, const float* __restrict__ Wk,
    const float* __restrict__ Wv, const float* __restrict__ Wp,
    const float* __restrict__ bq, const float* __restrict__ bk,
    const float* __restrict__ bv, const float* __restrict__ bp,
    const float* __restrict__ bt,
    ushort_t* __restrict__ Wqkv, ushort_t* __restrict__ Wpb,
    float* __restrict__ bqkv, float* __restrict__ bpb,
    ushort_t* __restrict__ bf)
{
    if (blockIdx.x < 257) {
        int idx = blockIdx.x * 256 + threadIdx.x;
        if (idx < 16384)       Wqkv[idx] = f2b(Wq[idx]);
        else if (idx < 32768)  Wqkv[idx] = f2b(Wk[idx - 16384]);
        else if (idx < 49152)  Wqkv[idx] = f2b(Wv[idx - 32768]);
        else if (idx < 65536)  Wpb[idx - 49152] = f2b(Wp[idx - 49152]);
        else {
            int e = idx - 65536;                 // 0..255, two elems each
            for (int k = e; k < 512; k += 256) {
                if (k < 128)      bqkv[k] = bq[k];
                else if (k < 256) bqkv[k] = bk[k - 128];
                else if (k < 384) bqkv[k] = bv[k - 256];
                else              bpb[k - 384] = bp[k - 384];
            }
        }
    } else {
        int idx  = (blockIdx.x - 257) * 256 + threadIdx.x;  // 0..262143
        int qt   = idx & 3;
        int lane = (idx >> 2) & 63;
        int wave = (idx >> 8) & 3;
        int kt   = (idx >> 10) & 63;
        int h    = (idx >> 16) & 3;
        int qrow  = wave * 4 + qt;
        int q     = qrow * 16 + (lane & 15);
        int kbase = kt * 16 + ((lane >> 4) << 2);
        unsigned v[4];
        #pragma unroll
        for (int r = 0; r < 4; ++r) {
            int key = kbase + r;
            int kr = key >> 5, kc = key & 31;
            int bidx = ((q >> 5) + 31 - kr) * 47 + (q & 31) - kc + 23;
            if (bidx < 0) bidx += BTBL;
            v[r] = f2b(bt[bidx * NHEADS + h] * LOG2E);
        }
        uint2 o;
        o.x = v[0] | (v[1] << 16);
        o.y = v[2] | (v[3] << 16);
        *(uint2*)&bf[(size_t)idx * 4] = o;
    }
}

// ---------------------------------------------------------------------------
// QKV GEMM: X fp32 [32768][128] -> Q/K/V all head-major [head][32768][32].
// Block tile 128M; 4 waves each 32M; nb looped internally.
__global__ __launch_bounds__(256) void gemm_qkv(
    const float* __restrict__ X, const ushort_t* __restrict__ W,
    const float* __restrict__ bias,
    ushort_t* __restrict__ Qb, ushort_t* __restrict__ Kb,
    ushort_t* __restrict__ Vb)
{
    __shared__ ushort_t Xs[128 * 136];

    const int t    = threadIdx.x;
    const int w    = t >> 6;
    const int lane = t & 63;
    const int quad = lane >> 4;
    const int l15  = lane & 15;
    const int m0   = blockIdx.x * 128;

    #pragma unroll
    for (int i = 0; i < 16; ++i) {
        int s = t + i * 256;
        int row = s >> 5, c4 = s & 31;
        float4 v = *(const float4*)&X[(size_t)(m0 + row) * 128 + c4 * 4];
        uint2 pk;
        pk.x = (unsigned)f2b(v.x) | ((unsigned)f2b(v.y) << 16);
        pk.y = (unsigned)f2b(v.z) | ((unsigned)f2b(v.w) << 16);
        *(uint2*)&Xs[row * 136 + c4 * 4] = pk;
    }
    __syncthreads();

    #pragma unroll 1
    for (int nb = 0; nb < 3; ++nb) {
        const float sc = (nb == 0) ? QSCALE : 1.0f;

        floatx4 acc[2][8];
        #pragma unroll
        for (int nt = 0; nt < 8; ++nt) {
            floatx4 bv = *(const floatx4*)&bias[nb * 128 + nt * 16 + quad * 4];
            acc[0][nt] = bv;
            acc[1][nt] = bv;
        }

        #pragma unroll
        for (int kc = 0; kc < 4; ++kc) {
            bf16x8 af[2], bfr[8];
            #pragma unroll
            for (int mt = 0; mt < 2; ++mt)
                af[mt] = *(const bf16x8*)&Xs[(w * 32 + mt * 16 + l15) * 136 + kc * 32 + quad * 8];
            #pragma unroll
            for (int nt = 0; nt < 8; ++nt)
                bfr[nt] = *(const bf16x8*)&W[(size_t)(nb * 128 + nt * 16 + l15) * 128 + kc * 32 + quad * 8];
            #pragma unroll
            for (int mt = 0; mt < 2; ++mt)
                #pragma unroll
                for (int nt = 0; nt < 8; ++nt)
                    acc[mt][nt] = __builtin_amdgcn_mfma_f32_16x16x32_bf16(bfr[nt], af[mt], acc[mt][nt], 0, 0, 0);
        }

        #pragma unroll
        for (int mt = 0; mt < 2; ++mt) {
            int m = m0 + w * 32 + mt * 16 + l15;
            #pragma unroll
            for (int nt = 0; nt < 8; ++nt) {
                int n = nt * 16 + quad * 4;          // 0..124, within 128 slice
                uint2 pk;
                pk.x = (unsigned)f2b(acc[mt][nt][0] * sc) |
                       ((unsigned)f2b(acc[mt][nt][1] * sc) << 16);
                pk.y = (unsigned)f2b(acc[mt][nt][2] * sc) |
                       ((unsigned)f2b(acc[mt][nt][3] * sc) << 16);
                // head-major: [head][pix][32], identical for Q/K/V
                size_t off = (((size_t)(n >> 5) << 15) + m) * 32 + (n & 31);
                if (nb == 0)      *(uint2*)&Qb[off] = pk;
                else if (nb == 1) *(uint2*)&Kb[off] = pk;
                else              *(uint2*)&Vb[off] = pk;
            }
        }
    }
}

// ---------------------------------------------------------------------------
// Proj GEMM: Ob head-major [4][32768][32] bf16 @ Wp^T + bp -> out fp32.
__global__ __launch_bounds__(256) void gemm_proj(
    const ushort_t* __restrict__ X, const ushort_t* __restrict__ W,
    const float* __restrict__ bias, float* __restrict__ out)
{
    __shared__ ushort_t Xs[128 * 136];

    const int t    = threadIdx.x;
    const int w    = t >> 6;
    const int lane = t & 63;
    const int quad = lane >> 4;
    const int l15  = lane & 15;
    const int m0   = blockIdx.x * 128;

    #pragma unroll
    for (int i = 0; i < 8; ++i) {
        int s = t + i * 256;
        int row = s >> 4, c8 = s & 15;
        int hd = c8 >> 2, d0 = (c8 & 3) * 8;
        *(int4*)&Xs[row * 136 + c8 * 8] =
            *(const int4*)&X[(((size_t)hd << 15) + m0 + row) * 32 + d0];
    }
    __syncthreads();

    floatx4 acc[2][8];
    #pragma unroll
    for (int nt = 0; nt < 8; ++nt) {
        floatx4 bv = *(const floatx4*)&bias[nt * 16 + quad * 4];
        acc[0][nt] = bv;
        acc[1][nt] = bv;
    }

    #pragma unroll
    for (int kc = 0; kc < 4; ++kc) {
        bf16x8 af[2], bfr[8];
        #pragma unroll
        for (int mt = 0; mt < 2; ++mt)
            af[mt] = *(const bf16x8*)&Xs[(w * 32 + mt * 16 + l15) * 136 + kc * 32 + quad * 8];
        #pragma unroll
        for (int nt = 0; nt < 8; ++nt)
            bfr[nt] = *(const bf16x8*)&W[(size_t)(nt * 16 + l15) * 128 + kc * 32 + quad * 8];
        #pragma unroll
        for (int mt = 0; mt < 2; ++mt)
            #pragma unroll
            for (int nt = 0; nt < 8; ++nt)
                acc[mt][nt] = __builtin_amdgcn_mfma_f32_16x16x32_bf16(bfr[nt], af[mt], acc[mt][nt], 0, 0, 0);
    }

    #pragma unroll
    for (int mt = 0; mt < 2; ++mt) {
        int m = m0 + w * 32 + mt * 16 + l15;
        #pragma unroll
        for (int nt = 0; nt < 8; ++nt) {
            int n = nt * 16 + quad * 4;
            float4 v;
            v.x = acc[mt][nt][0]; v.y = acc[mt][nt][1];
            v.z = acc[mt][nt][2]; v.w = acc[mt][nt][3];
            *(float4*)&out[(size_t)m * 128 + n] = v;
        }
    }
}

// ---------------------------------------------------------------------------
// One block per (window, head), XCD-swizzled: each XCD owns 64 windows of
// ONE head, ONE batch image (working set ~2MB, L2-resident). 4 independent
// waves, each owns 64 queries. R16 body with head-major Q/O.
__global__ __launch_bounds__(256, 2) void halo_attn(
    const ushort_t* __restrict__ Qb,   // [4][32768][32] bf16 (pre-scaled)
    const ushort_t* __restrict__ Kb,   // [4][32768][32] bf16
    const ushort_t* __restrict__ Vb,   // [4][32768][32] bf16
    const ushort_t* __restrict__ biasf,
    ushort_t* __restrict__ O)          // [4][32768][32] bf16 head-major
{
    __shared__ ushort_t P_lds[4 * 64 * PK];
    __shared__ ushort_t Vt_lds[4 * 32 * PK];

    const int t    = threadIdx.x;
    const int wave = t >> 6;
    const int lane = t & 63;
    const int quad = lane >> 4;
    const int l15  = lane & 15;
    const int swz  = (l15 & 7) << 3;   // row-derived XOR (row&7 == l15&7)

    // XCD swizzle: consecutive bids round-robin XCDs; each XCD gets 64
    // contiguous logical slots = 64 windows (one batch image) x 1 head.
    const int bid     = blockIdx.x;
    const int logical = (bid & 7) * 64 + (bid >> 3);
    const int head    = logical >> 7;
    const int win     = logical & 127;

    const int b    = win >> 6;
    const int wh   = (win >> 3) & 7;
    const int ww   = win & 7;
    const size_t hbase = (size_t)head << 15;    // head * 32768

    bf16x8 qf[4];
    int qpix[4];
    #pragma unroll
    for (int qt = 0; qt < 4; ++qt) {
        int q_abs = wave * 64 + qt * 16 + l15;
        int gy = wh * 16 + (q_abs >> 4), gx = ww * 16 + (q_abs & 15);
        int pix = (b * 128 + gy) * 128 + gx;
        qpix[qt] = pix;
        qf[qt] = *(const bf16x8*)(Qb + ((hbase + pix) << 5) + quad * 8);
    }

    floatx4 Oa[2][4];
    #pragma unroll
    for (int dt = 0; dt < 2; ++dt)
        #pragma unroll
        for (int qt = 0; qt < 4; ++qt)
            Oa[dt][qt] = (floatx4)0.f;
    float l[4] = {0.f, 0.f, 0.f, 0.f};

    ushort_t* Pw  = P_lds  + wave * 64 * PK;
    ushort_t* Vtw = Vt_lds + wave * 32 * PK;

    for (int c = 0; c < 16; ++c) {
        // ---- V chunk -> LDS transposed (per-wave): lane owns one key ----
        {
            int keyv = c * 64 + lane;
            int ky = reflect_idx(wh * 16 + (keyv >> 5) - 8);
            int kx = reflect_idx(ww * 16 + (keyv & 31) - 8);
            int pixv = (b * 128 + ky) * 128 + kx;
            const int4* vp4 = (const int4*)(Vb + ((hbase + pixv) << 5));
            int4 vw0 = vp4[0], vw1 = vp4[1], vw2 = vp4[2], vw3 = vp4[3];
            const ushort_t* vs0 = (const ushort_t*)&vw0;
            const ushort_t* vs1 = (const ushort_t*)&vw1;
            const ushort_t* vs2 = (const ushort_t*)&vw2;
            const ushort_t* vs3 = (const ushort_t*)&vw3;
            #pragma unroll
            for (int d = 0; d < 8; ++d) {
                int cs = lane ^ (d << 3);    // rows d,d+8,d+16,d+24: row&7 == d
                Vtw[(d +  0) * PK + cs] = vs0[d];
                Vtw[(d +  8) * PK + cs] = vs1[d];
                Vtw[(d + 16) * PK + cs] = vs2[d];
                Vtw[(d + 24) * PK + cs] = vs3[d];
            }
        }

        // ---- K A-fragments (coalesced: 16 consecutive pixels x 64B) ----
        bf16x8 kf[4];
        #pragma unroll
        for (int kt = 0; kt < 4; ++kt) {
            int key = c * 64 + kt * 16 + l15;
            int ky = reflect_idx(wh * 16 + (key >> 5) - 8);
            int kx = reflect_idx(ww * 16 + (key & 31) - 8);
            int pixk = (b * 128 + ky) * 128 + kx;
            kf[kt] = *(const bf16x8*)(Kb + ((hbase + pixk) << 5) + quad * 8);
        }

        // ---- S^T tiles: acc init = bias fragment (2 x b128 per kt) ----
        floatx4 S[4][4];
        #pragma unroll
        for (int kt = 0; kt < 4; ++kt) {
            int kt_abs = c * 4 + kt;
            size_t boff = ((((size_t)head * 64 + kt_abs) * 4 + wave) * 64 + lane) * 16;
            int4 blo = *(const int4*)&biasf[boff];
            int4 bhi = *(const int4*)&biasf[boff + 8];
            unsigned bx[4], by[4];
            bx[0] = (unsigned)blo.x; by[0] = (unsigned)blo.y;
            bx[1] = (unsigned)blo.z; by[1] = (unsigned)blo.w;
            bx[2] = (unsigned)bhi.x; by[2] = (unsigned)bhi.y;
            bx[3] = (unsigned)bhi.z; by[3] = (unsigned)bhi.w;
            #pragma unroll
            for (int qt = 0; qt < 4; ++qt) {
                floatx4 s;
                s[0] = __uint_as_float(bx[qt] << 16);
                s[1] = __uint_as_float(bx[qt] & 0xffff0000u);
                s[2] = __uint_as_float(by[qt] << 16);
                s[3] = __uint_as_float(by[qt] & 0xffff0000u);
                S[kt][qt] = s;
            }
        }
        #pragma unroll
        for (int kt = 0; kt < 4; ++kt)
            #pragma unroll
            for (int qt = 0; qt < 4; ++qt)
                S[kt][qt] = __builtin_amdgcn_mfma_f32_16x16x32_bf16(kf[kt], qf[qt], S[kt][qt], 0, 0, 0);

        // ---- exp2 + partial l + pack P (no max subtraction, no rescale) ----
        #pragma unroll
        for (int qt = 0; qt < 4; ++qt) {
            float ls = 0.f;
            #pragma unroll
            for (int kt = 0; kt < 4; ++kt) {
                #pragma unroll
                for (int r = 0; r < 4; ++r) {
                    float p = __builtin_amdgcn_exp2f(S[kt][qt][r]);
                    S[kt][qt][r] = p;
                    ls += p;
                }
            }
            l[qt] += ls;
            #pragma unroll
            for (int kt = 0; kt < 4; ++kt) {
                uint2 pk;
                pk.x = __builtin_amdgcn_perm(__float_as_uint(S[kt][qt][1]),
                                             __float_as_uint(S[kt][qt][0]), 0x07060302u);
                pk.y = __builtin_amdgcn_perm(__float_as_uint(S[kt][qt][3]),
                                             __float_as_uint(S[kt][qt][2]), 0x07060302u);
                *(uint2*)&Pw[(qt * 16 + l15) * PK + ((kt * 16 + quad * 4) ^ swz)] = pk;
            }
        }

        // ---- PV: O^T += V^T . P^T ----
        #pragma unroll
        for (int ks = 0; ks < 2; ++ks) {
            bf16x8 vf[2];
            #pragma unroll
            for (int dt = 0; dt < 2; ++dt)
                vf[dt] = *(const bf16x8*)&Vtw[(dt * 16 + l15) * PK + ((ks * 32 + quad * 8) ^ swz)];
            #pragma unroll
            for (int qt = 0; qt < 4; ++qt) {
                bf16x8 pf = *(const bf16x8*)&Pw[(qt * 16 + l15) * PK + ((ks * 32 + quad * 8) ^ swz)];
                #pragma unroll
                for (int dt = 0; dt < 2; ++dt)
                    Oa[dt][qt] = __builtin_amdgcn_mfma_f32_16x16x32_bf16(vf[dt], pf, Oa[dt][qt], 0, 0, 0);
            }
        }
    }

    // ---- epilogue: reduce l across quads, normalize, bf16 store ----
    #pragma unroll
    for (int qt = 0; qt < 4; ++qt) {
        float lq = l[qt];
        lq += __shfl_xor(lq, 16);
        lq += __shfl_xor(lq, 32);
        float inv = 1.0f / lq;
        #pragma unroll
        for (int dt = 0; dt < 2; ++dt) {
            uint2 pk;
            pk.x = (unsigned)f2b(Oa[dt][qt][0] * inv) | ((unsigned)f2b(Oa[dt][qt][1] * inv) << 16);
            pk.y = (unsigned)f2b(Oa[dt][qt][2] * inv) | ((unsigned)f2b(Oa[dt][qt][3] * inv) << 16);
            *(uint2*)(O + ((hbase + qpix[qt]) << 5) + dt * 16 + quad * 4) = pk;
        }
    }
}

// ---------------------------------------------------------------------------
extern "C" void kernel_launch(void* const* d_in, const int* in_sizes, int n_in,
                              void* d_out, int out_size, void* d_ws, size_t ws_size,
                              hipStream_t stream)
{
    const float* x          = (const float*)d_in[0];
    const float* Wq         = (const float*)d_in[1];
    const float* bq         = (const float*)d_in[2];
    const float* Wk         = (const float*)d_in[3];
    const float* bk         = (const float*)d_in[4];
    const float* Wv         = (const float*)d_in[5];
    const float* bv         = (const float*)d_in[6];
    const float* Wp         = (const float*)d_in[7];
    const float* bp         = (const float*)d_in[8];
    const float* bias_table = (const float*)d_in[9];
    float* out = (float*)d_out;

    char* ws = (char*)d_ws;
    ushort_t* Wqkv = (ushort_t*)(ws);                    // 98304 B
    ushort_t* Wpb  = (ushort_t*)(ws + 98304);            // 32768 B
    float*    bqkv = (float*)   (ws + 131072);           // 1536 B
    float*    bpb  = (float*)   (ws + 132608);           // 512 B
    ushort_t* Qb   = (ushort_t*)(ws + 133120);           // 8388608 B (head-major)
    ushort_t* Kb   = (ushort_t*)(ws + 8521728);          // 8388608 B (head-major)
    ushort_t* Vb   = (ushort_t*)(ws + 16910336);         // 8388608 B (head-major)
    ushort_t* Ob   = (ushort_t*)(ws + 25298944);         // 8388608 B (head-major)
    ushort_t* bf   = (ushort_t*)(ws + 33687552);         // 2097152 B (bf16)

    prep<<<dim3(1281), dim3(256), 0, stream>>>(Wq, Wk, Wv, Wp, bq, bk, bv, bp,
                                               bias_table, Wqkv, Wpb, bqkv, bpb, bf);
    gemm_qkv<<<dim3(256), dim3(256), 0, stream>>>(x, Wqkv, bqkv, Qb, Kb, Vb);
    halo_attn<<<dim3(512), dim3(256), 0, stream>>>(Qb, Kb, Vb, bf, Ob);
    gemm_proj<<<dim3(256), dim3(256), 0, stream>>>(Ob, Wpb, bpb, out);
}

// Round 14
// 153.193 us; speedup vs baseline: 1.0385x; 1.0385x over previous
//
#include <hip/hip_runtime.h>

// HaloAttention. B=2, H=W=128, C=128, NH=4, hd=32, WS=16, HS=8, WSH=32.
// R19 == R17 restored verbatim (measured best: halo 44.7us, total 154.7us).
// R18's deeper locality push (one head/XCD + head-major Q/O) cut FETCH
// 23.6->14.4MB but COST 2.2us: halo duration is decoupled from HBM traffic
// (6% of peak); the residual is per-load latency in the per-iteration serial
// chain, untouchable at HIP source level (R6/R10/R13/R14/R15 all regressed).
// Final configuration: R16 kernel body + T1 XCD swizzle (16 win x 4 heads
// per XCD), head-major K/V, XOR-swizzled aligned LDS (PK=64), consolidated
// b128 bias fragments, exp2-folded no-max softmax.

typedef unsigned short ushort_t;
typedef __attribute__((ext_vector_type(8))) short bf16x8;
typedef __attribute__((ext_vector_type(4))) float floatx4;

#define NHEADS 4
#define BTBL 2209          // 47*47 bias table rows
#define PK 64              // key stride (bf16) for P/Vt LDS rows (128B, aligned)
#define LOG2E 1.4426950408889634f
#define QSCALE (0.17677669529663687f * LOG2E)   // head_dim^-0.5 * log2(e)

__device__ __forceinline__ int reflect_idx(int p) {
    p = (p < 0) ? -p : p;
    p = (p > 127) ? 254 - p : p;
    return p;
}

// fp32 -> bf16 bits, RNE
__device__ __forceinline__ ushort_t f2b(float x) {
    unsigned u = __float_as_uint(x);
    return (ushort_t)((u + 0x7fffu + ((u >> 16) & 1u)) >> 16);
}

// ---------------------------------------------------------------------------
// Fused prep: blocks [0,257) pack weights/biases; blocks [257,1281) build the
// bf16 bias fragments (pre-scaled by log2e).
// Fragment layout: [h(4)][kt(64)][wave(4)][lane(64)][qt(4)][reg(4)] ushort.
__global__ __launch_bounds__(256) void prep(
    const float* __restrict__ Wq, const float* __restrict__ Wk,
    const float* __restrict__ Wv, const float* __restrict__ Wp,
    const float* __restrict__ bq, const float* __restrict__ bk,
    const float* __restrict__ bv, const float* __restrict__ bp,
    const float* __restrict__ bt,
    ushort_t* __restrict__ Wqkv, ushort_t* __restrict__ Wpb,
    float* __restrict__ bqkv, float* __restrict__ bpb,
    ushort_t* __restrict__ bf)
{
    if (blockIdx.x < 257) {
        int idx = blockIdx.x * 256 + threadIdx.x;
        if (idx < 16384)       Wqkv[idx] = f2b(Wq[idx]);
        else if (idx < 32768)  Wqkv[idx] = f2b(Wk[idx - 16384]);
        else if (idx < 49152)  Wqkv[idx] = f2b(Wv[idx - 32768]);
        else if (idx < 65536)  Wpb[idx - 49152] = f2b(Wp[idx - 49152]);
        else {
            int e = idx - 65536;                 // 0..255, two elems each
            for (int k = e; k < 512; k += 256) {
                if (k < 128)      bqkv[k] = bq[k];
                else if (k < 256) bqkv[k] = bk[k - 128];
                else if (k < 384) bqkv[k] = bv[k - 256];
                else              bpb[k - 384] = bp[k - 384];
            }
        }
    } else {
        int idx  = (blockIdx.x - 257) * 256 + threadIdx.x;  // 0..262143
        int qt   = idx & 3;
        int lane = (idx >> 2) & 63;
        int wave = (idx >> 8) & 3;
        int kt   = (idx >> 10) & 63;
        int h    = (idx >> 16) & 3;
        int qrow  = wave * 4 + qt;
        int q     = qrow * 16 + (lane & 15);
        int kbase = kt * 16 + ((lane >> 4) << 2);
        unsigned v[4];
        #pragma unroll
        for (int r = 0; r < 4; ++r) {
            int key = kbase + r;
            int kr = key >> 5, kc = key & 31;
            int bidx = ((q >> 5) + 31 - kr) * 47 + (q & 31) - kc + 23;
            if (bidx < 0) bidx += BTBL;
            v[r] = f2b(bt[bidx * NHEADS + h] * LOG2E);
        }
        uint2 o;
        o.x = v[0] | (v[1] << 16);
        o.y = v[2] | (v[3] << 16);
        *(uint2*)&bf[(size_t)idx * 4] = o;
    }
}

// ---------------------------------------------------------------------------
// QKV GEMM: X fp32 [32768][128] -> Q[pix][128] (scaled), K/V head-major
// [head][32768][32]. Block tile 128M; 4 waves each 32M; nb looped internally.
__global__ __launch_bounds__(256) void gemm_qkv(
    const float* __restrict__ X, const ushort_t* __restrict__ W,
    const float* __restrict__ bias,
    ushort_t* __restrict__ Qb, ushort_t* __restrict__ Kb,
    ushort_t* __restrict__ Vb)
{
    __shared__ ushort_t Xs[128 * 136];

    const int t    = threadIdx.x;
    const int w    = t >> 6;
    const int lane = t & 63;
    const int quad = lane >> 4;
    const int l15  = lane & 15;
    const int m0   = blockIdx.x * 128;

    #pragma unroll
    for (int i = 0; i < 16; ++i) {
        int s = t + i * 256;
        int row = s >> 5, c4 = s & 31;
        float4 v = *(const float4*)&X[(size_t)(m0 + row) * 128 + c4 * 4];
        uint2 pk;
        pk.x = (unsigned)f2b(v.x) | ((unsigned)f2b(v.y) << 16);
        pk.y = (unsigned)f2b(v.z) | ((unsigned)f2b(v.w) << 16);
        *(uint2*)&Xs[row * 136 + c4 * 4] = pk;
    }
    __syncthreads();

    #pragma unroll 1
    for (int nb = 0; nb < 3; ++nb) {
        const float sc = (nb == 0) ? QSCALE : 1.0f;

        floatx4 acc[2][8];
        #pragma unroll
        for (int nt = 0; nt < 8; ++nt) {
            floatx4 bv = *(const floatx4*)&bias[nb * 128 + nt * 16 + quad * 4];
            acc[0][nt] = bv;
            acc[1][nt] = bv;
        }

        #pragma unroll
        for (int kc = 0; kc < 4; ++kc) {
            bf16x8 af[2], bfr[8];
            #pragma unroll
            for (int mt = 0; mt < 2; ++mt)
                af[mt] = *(const bf16x8*)&Xs[(w * 32 + mt * 16 + l15) * 136 + kc * 32 + quad * 8];
            #pragma unroll
            for (int nt = 0; nt < 8; ++nt)
                bfr[nt] = *(const bf16x8*)&W[(size_t)(nb * 128 + nt * 16 + l15) * 128 + kc * 32 + quad * 8];
            #pragma unroll
            for (int mt = 0; mt < 2; ++mt)
                #pragma unroll
                for (int nt = 0; nt < 8; ++nt)
                    acc[mt][nt] = __builtin_amdgcn_mfma_f32_16x16x32_bf16(bfr[nt], af[mt], acc[mt][nt], 0, 0, 0);
        }

        #pragma unroll
        for (int mt = 0; mt < 2; ++mt) {
            int m = m0 + w * 32 + mt * 16 + l15;
            #pragma unroll
            for (int nt = 0; nt < 8; ++nt) {
                int n = nt * 16 + quad * 4;          // 0..124, within 128 slice
                uint2 pk;
                pk.x = (unsigned)f2b(acc[mt][nt][0] * sc) |
                       ((unsigned)f2b(acc[mt][nt][1] * sc) << 16);
                pk.y = (unsigned)f2b(acc[mt][nt][2] * sc) |
                       ((unsigned)f2b(acc[mt][nt][3] * sc) << 16);
                if (nb == 0) {
                    *(uint2*)&Qb[(size_t)m * 128 + n] = pk;
                } else {
                    // head-major: [head][pix][32]
                    size_t off = (((size_t)(n >> 5) << 15) + m) * 32 + (n & 31);
                    if (nb == 1) *(uint2*)&Kb[off] = pk;
                    else         *(uint2*)&Vb[off] = pk;
                }
            }
        }
    }
}

// ---------------------------------------------------------------------------
// Proj GEMM: Ob bf16 [32768][128] @ Wp^T + bp -> out fp32.
__global__ __launch_bounds__(256) void gemm_proj(
    const ushort_t* __restrict__ X, const ushort_t* __restrict__ W,
    const float* __restrict__ bias, float* __restrict__ out)
{
    __shared__ ushort_t Xs[128 * 136];

    const int t    = threadIdx.x;
    const int w    = t >> 6;
    const int lane = t & 63;
    const int quad = lane >> 4;
    const int l15  = lane & 15;
    const int m0   = blockIdx.x * 128;

    #pragma unroll
    for (int i = 0; i < 8; ++i) {
        int s = t + i * 256;
        int row = s >> 4, c8 = s & 15;
        *(int4*)&Xs[row * 136 + c8 * 8] =
            *(const int4*)&X[(size_t)(m0 + row) * 128 + c8 * 8];
    }
    __syncthreads();

    floatx4 acc[2][8];
    #pragma unroll
    for (int nt = 0; nt < 8; ++nt) {
        floatx4 bv = *(const floatx4*)&bias[nt * 16 + quad * 4];
        acc[0][nt] = bv;
        acc[1][nt] = bv;
    }

    #pragma unroll
    for (int kc = 0; kc < 4; ++kc) {
        bf16x8 af[2], bfr[8];
        #pragma unroll
        for (int mt = 0; mt < 2; ++mt)
            af[mt] = *(const bf16x8*)&Xs[(w * 32 + mt * 16 + l15) * 136 + kc * 32 + quad * 8];
        #pragma unroll
        for (int nt = 0; nt < 8; ++nt)
            bfr[nt] = *(const bf16x8*)&W[(size_t)(nt * 16 + l15) * 128 + kc * 32 + quad * 8];
        #pragma unroll
        for (int mt = 0; mt < 2; ++mt)
            #pragma unroll
            for (int nt = 0; nt < 8; ++nt)
                acc[mt][nt] = __builtin_amdgcn_mfma_f32_16x16x32_bf16(bfr[nt], af[mt], acc[mt][nt], 0, 0, 0);
    }

    #pragma unroll
    for (int mt = 0; mt < 2; ++mt) {
        int m = m0 + w * 32 + mt * 16 + l15;
        #pragma unroll
        for (int nt = 0; nt < 8; ++nt) {
            int n = nt * 16 + quad * 4;
            float4 v;
            v.x = acc[mt][nt][0]; v.y = acc[mt][nt][1];
            v.z = acc[mt][nt][2]; v.w = acc[mt][nt][3];
            *(float4*)&out[(size_t)m * 128 + n] = v;
        }
    }
}

// ---------------------------------------------------------------------------
// One block per (window, head), XCD-swizzled: each XCD owns 16 contiguous
// windows x 4 heads so the shared halo K/V working set fits its private L2.
// 4 independent waves, each owns 64 queries.
__global__ __launch_bounds__(256, 2) void halo_attn(
    const ushort_t* __restrict__ Qb,   // [32768][128] bf16 (pre-scaled)
    const ushort_t* __restrict__ Kb,   // [4][32768][32] bf16
    const ushort_t* __restrict__ Vb,   // [4][32768][32] bf16
    const ushort_t* __restrict__ biasf,
    ushort_t* __restrict__ O)          // [32768][128] bf16
{
    __shared__ ushort_t P_lds[4 * 64 * PK];
    __shared__ ushort_t Vt_lds[4 * 32 * PK];

    const int t    = threadIdx.x;
    const int wave = t >> 6;
    const int lane = t & 63;
    const int quad = lane >> 4;
    const int l15  = lane & 15;
    const int swz  = (l15 & 7) << 3;   // row-derived XOR (row&7 == l15&7)

    // XCD swizzle: consecutive bids round-robin XCDs; give each XCD a
    // contiguous chunk of 64 logical slots = 16 windows x 4 heads.
    const int bid     = blockIdx.x;
    const int logical = (bid & 7) * 64 + (bid >> 3);
    const int head    = logical & 3;
    const int win     = logical >> 2;

    const int b    = win >> 6;
    const int wh   = (win >> 3) & 7;
    const int ww   = win & 7;
    const size_t hbase = (size_t)head << 15;    // head * 32768

    bf16x8 qf[4];
    int qpix[4];
    #pragma unroll
    for (int qt = 0; qt < 4; ++qt) {
        int q_abs = wave * 64 + qt * 16 + l15;
        int gy = wh * 16 + (q_abs >> 4), gx = ww * 16 + (q_abs & 15);
        int pix = (b * 128 + gy) * 128 + gx;
        qpix[qt] = pix;
        qf[qt] = *(const bf16x8*)(Qb + (size_t)pix * 128 + head * 32 + quad * 8);
    }

    floatx4 Oa[2][4];
    #pragma unroll
    for (int dt = 0; dt < 2; ++dt)
        #pragma unroll
        for (int qt = 0; qt < 4; ++qt)
            Oa[dt][qt] = (floatx4)0.f;
    float l[4] = {0.f, 0.f, 0.f, 0.f};

    ushort_t* Pw  = P_lds  + wave * 64 * PK;
    ushort_t* Vtw = Vt_lds + wave * 32 * PK;

    for (int c = 0; c < 16; ++c) {
        // ---- V chunk -> LDS transposed (per-wave): lane owns one key ----
        {
            int keyv = c * 64 + lane;
            int ky = reflect_idx(wh * 16 + (keyv >> 5) - 8);
            int kx = reflect_idx(ww * 16 + (keyv & 31) - 8);
            int pixv = (b * 128 + ky) * 128 + kx;
            const int4* vp4 = (const int4*)(Vb + ((hbase + pixv) << 5));
            int4 vw0 = vp4[0], vw1 = vp4[1], vw2 = vp4[2], vw3 = vp4[3];
            const ushort_t* vs0 = (const ushort_t*)&vw0;
            const ushort_t* vs1 = (const ushort_t*)&vw1;
            const ushort_t* vs2 = (const ushort_t*)&vw2;
            const ushort_t* vs3 = (const ushort_t*)&vw3;
            #pragma unroll
            for (int d = 0; d < 8; ++d) {
                int cs = lane ^ (d << 3);    // rows d,d+8,d+16,d+24: row&7 == d
                Vtw[(d +  0) * PK + cs] = vs0[d];
                Vtw[(d +  8) * PK + cs] = vs1[d];
                Vtw[(d + 16) * PK + cs] = vs2[d];
                Vtw[(d + 24) * PK + cs] = vs3[d];
            }
        }

        // ---- K A-fragments (coalesced: 16 consecutive pixels x 64B) ----
        bf16x8 kf[4];
        #pragma unroll
        for (int kt = 0; kt < 4; ++kt) {
            int key = c * 64 + kt * 16 + l15;
            int ky = reflect_idx(wh * 16 + (key >> 5) - 8);
            int kx = reflect_idx(ww * 16 + (key & 31) - 8);
            int pixk = (b * 128 + ky) * 128 + kx;
            kf[kt] = *(const bf16x8*)(Kb + ((hbase + pixk) << 5) + quad * 8);
        }

        // ---- S^T tiles: acc init = bias fragment (2 x b128 per kt) ----
        floatx4 S[4][4];
        #pragma unroll
        for (int kt = 0; kt < 4; ++kt) {
            int kt_abs = c * 4 + kt;
            size_t boff = ((((size_t)head * 64 + kt_abs) * 4 + wave) * 64 + lane) * 16;
            int4 blo = *(const int4*)&biasf[boff];
            int4 bhi = *(const int4*)&biasf[boff + 8];
            unsigned bx[4], by[4];
            bx[0] = (unsigned)blo.x; by[0] = (unsigned)blo.y;
            bx[1] = (unsigned)blo.z; by[1] = (unsigned)blo.w;
            bx[2] = (unsigned)bhi.x; by[2] = (unsigned)bhi.y;
            bx[3] = (unsigned)bhi.z; by[3] = (unsigned)bhi.w;
            #pragma unroll
            for (int qt = 0; qt < 4; ++qt) {
                floatx4 s;
                s[0] = __uint_as_float(bx[qt] << 16);
                s[1] = __uint_as_float(bx[qt] & 0xffff0000u);
                s[2] = __uint_as_float(by[qt] << 16);
                s[3] = __uint_as_float(by[qt] & 0xffff0000u);
                S[kt][qt] = s;
            }
        }
        #pragma unroll
        for (int kt = 0; kt < 4; ++kt)
            #pragma unroll
            for (int qt = 0; qt < 4; ++qt)
                S[kt][qt] = __builtin_amdgcn_mfma_f32_16x16x32_bf16(kf[kt], qf[qt], S[kt][qt], 0, 0, 0);

        // ---- exp2 + partial l + pack P (no max subtraction, no rescale) ----
        #pragma unroll
        for (int qt = 0; qt < 4; ++qt) {
            float ls = 0.f;
            #pragma unroll
            for (int kt = 0; kt < 4; ++kt) {
                #pragma unroll
                for (int r = 0; r < 4; ++r) {
                    float p = __builtin_amdgcn_exp2f(S[kt][qt][r]);
                    S[kt][qt][r] = p;
                    ls += p;
                }
            }
            l[qt] += ls;
            #pragma unroll
            for (int kt = 0; kt < 4; ++kt) {
                uint2 pk;
                pk.x = __builtin_amdgcn_perm(__float_as_uint(S[kt][qt][1]),
                                             __float_as_uint(S[kt][qt][0]), 0x07060302u);
                pk.y = __builtin_amdgcn_perm(__float_as_uint(S[kt][qt][3]),
                                             __float_as_uint(S[kt][qt][2]), 0x07060302u);
                *(uint2*)&Pw[(qt * 16 + l15) * PK + ((kt * 16 + quad * 4) ^ swz)] = pk;
            }
        }

        // ---- PV: O^T += V^T . P^T ----
        #pragma unroll
        for (int ks = 0; ks < 2; ++ks) {
            bf16x8 vf[2];
            #pragma unroll
            for (int dt = 0; dt < 2; ++dt)
                vf[dt] = *(const bf16x8*)&Vtw[(dt * 16 + l15) * PK + ((ks * 32 + quad * 8) ^ swz)];
            #pragma unroll
            for (int qt = 0; qt < 4; ++qt) {
                bf16x8 pf = *(const bf16x8*)&Pw[(qt * 16 + l15) * PK + ((ks * 32 + quad * 8) ^ swz)];
                #pragma unroll
                for (int dt = 0; dt < 2; ++dt)
                    Oa[dt][qt] = __builtin_amdgcn_mfma_f32_16x16x32_bf16(vf[dt], pf, Oa[dt][qt], 0, 0, 0);
            }
        }
    }

    // ---- epilogue: reduce l across quads, normalize, bf16 store ----
    #pragma unroll
    for (int qt = 0; qt < 4; ++qt) {
        float lq = l[qt];
        lq += __shfl_xor(lq, 16);
        lq += __shfl_xor(lq, 32);
        float inv = 1.0f / lq;
        #pragma unroll
        for (int dt = 0; dt < 2; ++dt) {
            uint2 pk;
            pk.x = (unsigned)f2b(Oa[dt][qt][0] * inv) | ((unsigned)f2b(Oa[dt][qt][1] * inv) << 16);
            pk.y = (unsigned)f2b(Oa[dt][qt][2] * inv) | ((unsigned)f2b(Oa[dt][qt][3] * inv) << 16);
            *(uint2*)(O + (size_t)qpix[qt] * 128 + head * 32 + dt * 16 + quad * 4) = pk;
        }
    }
}

// ---------------------------------------------------------------------------
extern "C" void kernel_launch(void* const* d_in, const int* in_sizes, int n_in,
                              void* d_out, int out_size, void* d_ws, size_t ws_size,
                              hipStream_t stream)
{
    const float* x          = (const float*)d_in[0];
    const float* Wq         = (const float*)d_in[1];
    const float* bq         = (const float*)d_in[2];
    const float* Wk         = (const float*)d_in[3];
    const float* bk         = (const float*)d_in[4];
    const float* Wv         = (const float*)d_in[5];
    const float* bv         = (const float*)d_in[6];
    const float* Wp         = (const float*)d_in[7];
    const float* bp         = (const float*)d_in[8];
    const float* bias_table = (const float*)d_in[9];
    float* out = (float*)d_out;

    char* ws = (char*)d_ws;
    ushort_t* Wqkv = (ushort_t*)(ws);                    // 98304 B
    ushort_t* Wpb  = (ushort_t*)(ws + 98304);            // 32768 B
    float*    bqkv = (float*)   (ws + 131072);           // 1536 B
    float*    bpb  = (float*)   (ws + 132608);           // 512 B
    ushort_t* Qb   = (ushort_t*)(ws + 133120);           // 8388608 B
    ushort_t* Kb   = (ushort_t*)(ws + 8521728);          // 8388608 B (head-major)
    ushort_t* Vb   = (ushort_t*)(ws + 16910336);         // 8388608 B (head-major)
    ushort_t* Ob   = (ushort_t*)(ws + 25298944);         // 8388608 B
    ushort_t* bf   = (ushort_t*)(ws + 33687552);         // 2097152 B (bf16)

    prep<<<dim3(1281), dim3(256), 0, stream>>>(Wq, Wk, Wv, Wp, bq, bk, bv, bp,
                                               bias_table, Wqkv, Wpb, bqkv, bpb, bf);
    gemm_qkv<<<dim3(256), dim3(256), 0, stream>>>(x, Wqkv, bqkv, Qb, Kb, Vb);
    halo_attn<<<dim3(512), dim3(256), 0, stream>>>(Qb, Kb, Vb, bf, Ob);
    gemm_proj<<<dim3(256), dim3(256), 0, stream>>>(Ob, Wpb, bpb, out);
}